// Round 11
// baseline (214.557 us; speedup 1.0000x reference)
//
#include <hip/hip_runtime.h>
#include <hip/hip_fp16.h>

// ---------------------------------------------------------------------------
// GCN layer: out[b][f][t][n] = relu( rsqrt(deg_in[n]) *
//     sum_{e: dst[e]=n} ( rsqrt(deg_out[src[e]]) * x[src[e]] @ W )[b][t][f] + bias[f] )
// Strategy: (1) degrees+CSR, (2) GEMV-style transform -> y[n][512] fp16
//           node-major PERMUTED, (3) CSR gather-sum + epilogue + transpose.
// R11: y channel-permuted so ONE uint4/edge yields channels {4l..4l+3,
//      256+4l..256+4l+3} -> agg LDS stores back to 8-way layout (R10's 16-way
//      conflict fixed) with R10's halved load count. Edge unroll 8.
//      Setup: hipMemsetAsync for zeroing, rsqrt fused into scan1.
// y layout: row n = uint4[64]; uint4[l] fp16s = channels
//      (4l,4l+1,4l+2,4l+3, 256+4l,...,256+4l+3).  c<256: pos=8*(c>>2)+(c&3);
//      c>=256: pos=8*((c-256)>>2)+4+((c-256)&3).
// ---------------------------------------------------------------------------

extern "C" __global__ void k_deg(const int* __restrict__ src, const int* __restrict__ dst,
                                 int* __restrict__ deg_out, int* __restrict__ deg_in, int E) {
  int e = blockIdx.x * blockDim.x + threadIdx.x;
  if (e < E) {
    atomicAdd(&deg_out[src[e]], 1);
    atomicAdd(&deg_in[dst[e]], 1);
  }
}

// scan1 + rsqrt fused: block sums of deg_in, plus rs arrays.
extern "C" __global__ __launch_bounds__(256) void k_scan1(const int* __restrict__ deg_in,
                                                          const int* __restrict__ deg_out,
                                                          int* __restrict__ bsum,
                                                          float* __restrict__ rs_out,
                                                          float* __restrict__ rs_in, int N) {
  __shared__ int red[256];
  int tid = threadIdx.x;
  int i = blockIdx.x * 256 + tid;
  int di = (i < N) ? deg_in[i] : 0;
  red[tid] = di;
  if (i < N) {
    int a = deg_out[i] > 1 ? deg_out[i] : 1;
    int b = di > 1 ? di : 1;
    rs_out[i] = rsqrtf((float)a);
    rs_in[i]  = rsqrtf((float)b);
  }
  __syncthreads();
  #pragma unroll
  for (int off = 128; off > 0; off >>= 1) {
    if (tid < off) red[tid] += red[tid + off];
    __syncthreads();
  }
  if (tid == 0) bsum[blockIdx.x] = red[0];
}

extern "C" __global__ __launch_bounds__(256) void k_scan2(const int* __restrict__ bsum,
                                                          int* __restrict__ boffs,
                                                          int* __restrict__ offs, int M, int N) {
  __shared__ int sc[256];
  int tid = threadIdx.x;
  int v = (tid < M) ? bsum[tid] : 0;
  sc[tid] = v;
  __syncthreads();
  #pragma unroll
  for (int off = 1; off < 256; off <<= 1) {
    int t = sc[tid];
    if (tid >= off) t += sc[tid - off];
    __syncthreads();
    sc[tid] = t;
    __syncthreads();
  }
  boffs[tid] = sc[tid] - v;           // exclusive block offset
  if (tid == 255) offs[N] = sc[255];  // total edge count
}

extern "C" __global__ __launch_bounds__(256) void k_scan3(const int* __restrict__ deg,
                                                          const int* __restrict__ boffs,
                                                          int* __restrict__ offs, int N) {
  __shared__ int sc[256];
  int tid = threadIdx.x;
  int i = blockIdx.x * 256 + tid;
  int v = (i < N) ? deg[i] : 0;
  sc[tid] = v;
  __syncthreads();
  #pragma unroll
  for (int off = 1; off < 256; off <<= 1) {
    int t = sc[tid];
    if (tid >= off) t += sc[tid - off];
    __syncthreads();
    sc[tid] = t;
    __syncthreads();
  }
  if (i < N) offs[i] = boffs[blockIdx.x] + sc[tid] - v;
}

extern "C" __global__ void k_scatter(const int* __restrict__ src, const int* __restrict__ dst,
                                     const int* __restrict__ offs, int* __restrict__ cursor,
                                     int* __restrict__ csr_src, int E) {
  int e = blockIdx.x * blockDim.x + threadIdx.x;
  if (e < E) {
    int d = dst[e];
    int pos = offs[d] + atomicAdd(&cursor[d], 1);
    csr_src[pos] = src[e];
  }
}

// Transform: wave = 64 nodes (lane = node) x one bt x 32 f's, cross-iteration
// prefetch (R9). Stores into the PERMUTED y layout: acc[4q..4q+3] packs to
// one 8B chunk at fp16-offset (l0+q)*8 + hi, l0=(bt&3)*16+(fh>>2),
// hi = (bt>=4)?4:0.  VGPR ~36-40; bigger per-thread tiles spill (R6/R8).
extern "C" __global__ __launch_bounds__(256) void k_transform(
    const float* __restrict__ in_feat, const float* __restrict__ W,
    const float* __restrict__ rs_out, __half* __restrict__ y, int N) {
  int tid = threadIdx.x;
  int wave = tid >> 6, lane = tid & 63;
  int bt = blockIdx.y * 4 + wave;     // 0..7
  int b = bt >> 2, t = bt & 3;
  int fh = blockIdx.z * 32;           // f half: 0 or 32
  int n = blockIdx.x * 64 + lane;

  const float* xp = in_feat + (size_t)(b * 256 + t) * (size_t)N;  // h=0 row
  size_t hstride = (size_t)4 * (size_t)N;

  float acc[32];
  #pragma unroll
  for (int f = 0; f < 32; ++f) acc[f] = 0.0f;

  bool ok = (n < N);

  float xcur[4], xnxt[4];
  #pragma unroll
  for (int u = 0; u < 4; ++u)
    xcur[u] = ok ? xp[(size_t)u * hstride + n] : 0.0f;

  #pragma unroll 1
  for (int h0 = 0; h0 < 60; h0 += 4) {
    #pragma unroll
    for (int u = 0; u < 4; ++u)
      xnxt[u] = ok ? xp[(size_t)(h0 + 4 + u) * hstride + n] : 0.0f;
    #pragma unroll
    for (int u = 0; u < 4; ++u) {
      const float* wrow = W + (h0 + u) * 64 + fh;   // uniform -> s_load
      #pragma unroll
      for (int f = 0; f < 32; ++f) acc[f] = fmaf(xcur[u], wrow[f], acc[f]);
    }
    #pragma unroll
    for (int u = 0; u < 4; ++u) xcur[u] = xnxt[u];
  }
  #pragma unroll
  for (int u = 0; u < 4; ++u) {
    const float* wrow = W + (60 + u) * 64 + fh;
    #pragma unroll
    for (int f = 0; f < 32; ++f) acc[f] = fmaf(xcur[u], wrow[f], acc[f]);
  }

  if (ok) {
    float rs = rs_out[n];
    __half* rowp = y + (size_t)n * 512;
    int l0 = (bt & 3) * 16 + (fh >> 2);
    int hi = (bt >= 4) ? 4 : 0;
    #pragma unroll
    for (int q = 0; q < 8; ++q) {
      __half2 h0 = __float22half2_rn(make_float2(acc[4 * q] * rs, acc[4 * q + 1] * rs));
      __half2 h1 = __float22half2_rn(make_float2(acc[4 * q + 2] * rs, acc[4 * q + 3] * rs));
      uint2 u;
      u.x = *(unsigned int*)&h0;
      u.y = *(unsigned int*)&h1;
      *(uint2*)(rowp + (l0 + q) * 8 + hi) = u;
    }
  }
}

// Aggregate: 512 threads = 8 waves; wave handles 2 nodes (16-node tile, 33KB
// LDS -> 4 blocks/CU -> 32 waves/CU). Per edge: ONE uint4 (permuted y row) ->
// accA = channels 4l..4l+3, accB = 256+4l..+3; LDS stores at lane*4 /
// 256+lane*4 (8-way, the R9 conflict level). Edge unroll 8 = 8KB in flight.
extern "C" __global__ __launch_bounds__(512) void k_aggregate(
    const __half* __restrict__ y, const int* __restrict__ offs,
    const int* __restrict__ csr_src, const float* __restrict__ rs_in,
    const float* __restrict__ bvec, float* __restrict__ out, int N) {
  __shared__ float agg[16 * 513];
  int tid = threadIdx.x;
  int lane = tid & 63, wave = tid >> 6;   // 8 waves
  int n0 = blockIdx.x * 16;

#define LDE(i, s) uint4 u##i = ((const uint4*)(y + (size_t)(s) * 512))[lane];
#define ADE(i)                                                               \
  {                                                                          \
    float2 f;                                                                \
    f = __half22float2(*(const __half2*)&u##i.x); accA.x += f.x; accA.y += f.y; \
    f = __half22float2(*(const __half2*)&u##i.y); accA.z += f.x; accA.w += f.y; \
    f = __half22float2(*(const __half2*)&u##i.z); accB.x += f.x; accB.y += f.y; \
    f = __half22float2(*(const __half2*)&u##i.w); accB.z += f.x; accB.w += f.y; \
  }

  #pragma unroll
  for (int k = 0; k < 2; ++k) {
    int nl = k * 8 + wave;
    int n = n0 + nl;
    float4 accA = {0.f, 0.f, 0.f, 0.f};
    float4 accB = {0.f, 0.f, 0.f, 0.f};
    if (n < N) {
      int j0 = offs[n], j1 = offs[n + 1];
      for (int base = j0; base < j1; base += 64) {
        int idxv = csr_src[base + lane];  // coalesced block of up to 64 indices
        int m = j1 - base; if (m > 64) m = 64;
        int e = 0;
        for (; e + 7 < m; e += 8) {
          int s0 = __builtin_amdgcn_readlane(idxv, e);
          int s1 = __builtin_amdgcn_readlane(idxv, e + 1);
          int s2 = __builtin_amdgcn_readlane(idxv, e + 2);
          int s3 = __builtin_amdgcn_readlane(idxv, e + 3);
          int s4 = __builtin_amdgcn_readlane(idxv, e + 4);
          int s5 = __builtin_amdgcn_readlane(idxv, e + 5);
          int s6 = __builtin_amdgcn_readlane(idxv, e + 6);
          int s7 = __builtin_amdgcn_readlane(idxv, e + 7);
          LDE(0, s0); LDE(1, s1); LDE(2, s2); LDE(3, s3);
          LDE(4, s4); LDE(5, s5); LDE(6, s6); LDE(7, s7);
          ADE(0); ADE(1); ADE(2); ADE(3); ADE(4); ADE(5); ADE(6); ADE(7);
        }
        for (; e + 3 < m; e += 4) {
          int s0 = __builtin_amdgcn_readlane(idxv, e);
          int s1 = __builtin_amdgcn_readlane(idxv, e + 1);
          int s2 = __builtin_amdgcn_readlane(idxv, e + 2);
          int s3 = __builtin_amdgcn_readlane(idxv, e + 3);
          LDE(0, s0); LDE(1, s1); LDE(2, s2); LDE(3, s3);
          ADE(0); ADE(1); ADE(2); ADE(3);
        }
        for (; e < m; ++e) {
          int s0 = __builtin_amdgcn_readlane(idxv, e);
          LDE(0, s0); ADE(0);
        }
      }
    }
    *(float4*)&agg[nl * 513 + lane * 4] = accA;
    *(float4*)&agg[nl * 513 + 256 + lane * 4] = accB;
  }
#undef LDE
#undef ADE
  __syncthreads();

  // epilogue: scale, bias, relu, transpose-back to channel-major
  int nl = tid & 15;
  int r0 = tid >> 4;  // 0..31
  int n = n0 + nl;
  float rs = (n < N) ? rs_in[n] : 0.0f;
  #pragma unroll 4
  for (int it = 0; it < 16; ++it) {
    int c = it * 32 + r0;          // c = (b*4+t)*64 + f
    float v = agg[nl * 513 + c];
    int f = c & 63, bt = c >> 6;
    int b = bt >> 2, t = bt & 3;
    v = v * rs + bvec[f];
    v = fmaxf(v, 0.0f);
    if (n < N) out[(size_t)((b * 64 + f) * 4 + t) * (size_t)N + n] = v;
  }
}

extern "C" void kernel_launch(void* const* d_in, const int* in_sizes, int n_in,
                              void* d_out, int out_size, void* d_ws, size_t ws_size,
                              hipStream_t stream) {
  const float* in_feat = (const float*)d_in[0];
  const int*   src     = (const int*)d_in[1];
  const int*   dst     = (const int*)d_in[2];
  const float* W       = (const float*)d_in[3];
  const float* bvec    = (const float*)d_in[4];
  float* out = (float*)d_out;

  int N = in_sizes[0] / 512;   // B*H*T = 2*64*4 = 512
  int E = in_sizes[1];

  int A  = (N + 64) & ~63;     // room for N+1 offsets, 64-aligned
  int EA = (E + 63) & ~63;
  int M  = (N + 255) / 256;    // scan blocks (<= 256 for N <= 65536)

  // layout: the three arrays needing zero-init come first (one memset)
  int*   deg_out_i = (int*)d_ws;        // [A]  zeroed
  int*   deg_in_i  = deg_out_i + A;     // [A]  zeroed
  int*   cursor    = deg_in_i + A;      // [A]  zeroed
  int*   offs      = cursor + A;        // [A] (N+1 used, fully written by scans)
  int*   bsum      = offs + A;          // [256]
  int*   boffs     = bsum + 256;        // [256]
  float* rs_out    = (float*)(boffs + 256);
  float* rs_in     = rs_out + A;
  int*   csr_src   = (int*)(rs_in + A); // [EA] (+slack: y follows, overreads safe)
  __half* y        = (__half*)(csr_src + EA); // [N*512] fp16, permuted layout

  hipMemsetAsync(deg_out_i, 0, (size_t)(3 * A) * sizeof(int), stream);
  hipLaunchKernelGGL(k_deg, dim3((E + 255) / 256), dim3(256), 0, stream,
                     src, dst, deg_out_i, deg_in_i, E);
  hipLaunchKernelGGL(k_scan1, dim3(M), dim3(256), 0, stream,
                     deg_in_i, deg_out_i, bsum, rs_out, rs_in, N);
  hipLaunchKernelGGL(k_scan2, dim3(1), dim3(256), 0, stream, bsum, boffs, offs, M, N);
  hipLaunchKernelGGL(k_scan3, dim3(M), dim3(256), 0, stream, deg_in_i, boffs, offs, N);
  hipLaunchKernelGGL(k_scatter, dim3((E + 255) / 256), dim3(256), 0, stream,
                     src, dst, offs, cursor, csr_src, E);
  hipLaunchKernelGGL(k_transform, dim3((N + 63) / 64, 2, 2), dim3(256), 0, stream,
                     in_feat, W, rs_out, y, N);
  hipLaunchKernelGGL(k_aggregate, dim3((N + 15) / 16), dim3(512), 0, stream,
                     y, offs, csr_src, rs_in, bvec, out, N);
}

// Round 12
// 199.412 us; speedup vs baseline: 1.0759x; 1.0759x over previous
//
#include <hip/hip_runtime.h>
#include <hip/hip_fp16.h>

// ---------------------------------------------------------------------------
// GCN layer: out[b][f][t][n] = relu( rsqrt(deg_in[n]) *
//     sum_{e: dst[e]=n} ( rsqrt(deg_out[src[e]]) * x[src[e]] @ W )[b][t][f] + bias[f] )
// Strategy: (1) degrees+CSR, (2) GEMV-style transform -> y[n][512] fp16 PLAIN
//           node-major, (3) CSR gather (1 uint4/edge) + LDS-permuted store +
//           epilogue remap + transpose-back.
// R12: R11's y-permutation moved into aggregate's LDS column mapping.
//      y PLAIN again -> transform does contiguous 64B/thread stores (R11's
//      2x write amplification gone). Aggregate: uint4/edge (R10's halved
//      loads), accA->col 4l, accB->col 256+4l (8-way conflict level of R9),
//      epilogue reads col(c) = (c&4)? 256+4*(c>>3)+(c&3) : 4*(c>>3)+(c&3).
// ---------------------------------------------------------------------------

extern "C" __global__ void k_deg(const int* __restrict__ src, const int* __restrict__ dst,
                                 int* __restrict__ deg_out, int* __restrict__ deg_in, int E) {
  int e = blockIdx.x * blockDim.x + threadIdx.x;
  if (e < E) {
    atomicAdd(&deg_out[src[e]], 1);
    atomicAdd(&deg_in[dst[e]], 1);
  }
}

// scan1 + rsqrt fused: block sums of deg_in, plus rs arrays.
extern "C" __global__ __launch_bounds__(256) void k_scan1(const int* __restrict__ deg_in,
                                                          const int* __restrict__ deg_out,
                                                          int* __restrict__ bsum,
                                                          float* __restrict__ rs_out,
                                                          float* __restrict__ rs_in, int N) {
  __shared__ int red[256];
  int tid = threadIdx.x;
  int i = blockIdx.x * 256 + tid;
  int di = (i < N) ? deg_in[i] : 0;
  red[tid] = di;
  if (i < N) {
    int a = deg_out[i] > 1 ? deg_out[i] : 1;
    int b = di > 1 ? di : 1;
    rs_out[i] = rsqrtf((float)a);
    rs_in[i]  = rsqrtf((float)b);
  }
  __syncthreads();
  #pragma unroll
  for (int off = 128; off > 0; off >>= 1) {
    if (tid < off) red[tid] += red[tid + off];
    __syncthreads();
  }
  if (tid == 0) bsum[blockIdx.x] = red[0];
}

extern "C" __global__ __launch_bounds__(256) void k_scan2(const int* __restrict__ bsum,
                                                          int* __restrict__ boffs,
                                                          int* __restrict__ offs, int M, int N) {
  __shared__ int sc[256];
  int tid = threadIdx.x;
  int v = (tid < M) ? bsum[tid] : 0;
  sc[tid] = v;
  __syncthreads();
  #pragma unroll
  for (int off = 1; off < 256; off <<= 1) {
    int t = sc[tid];
    if (tid >= off) t += sc[tid - off];
    __syncthreads();
    sc[tid] = t;
    __syncthreads();
  }
  boffs[tid] = sc[tid] - v;           // exclusive block offset
  if (tid == 255) offs[N] = sc[255];  // total edge count
}

extern "C" __global__ __launch_bounds__(256) void k_scan3(const int* __restrict__ deg,
                                                          const int* __restrict__ boffs,
                                                          int* __restrict__ offs, int N) {
  __shared__ int sc[256];
  int tid = threadIdx.x;
  int i = blockIdx.x * 256 + tid;
  int v = (i < N) ? deg[i] : 0;
  sc[tid] = v;
  __syncthreads();
  #pragma unroll
  for (int off = 1; off < 256; off <<= 1) {
    int t = sc[tid];
    if (tid >= off) t += sc[tid - off];
    __syncthreads();
    sc[tid] = t;
    __syncthreads();
  }
  if (i < N) offs[i] = boffs[blockIdx.x] + sc[tid] - v;
}

extern "C" __global__ void k_scatter(const int* __restrict__ src, const int* __restrict__ dst,
                                     const int* __restrict__ offs, int* __restrict__ cursor,
                                     int* __restrict__ csr_src, int E) {
  int e = blockIdx.x * blockDim.x + threadIdx.x;
  if (e < E) {
    int d = dst[e];
    int pos = offs[d] + atomicAdd(&cursor[d], 1);
    csr_src[pos] = src[e];
  }
}

// Transform (R9 known-good): wave = 64 nodes (lane = node) x one bt x 32 f's,
// cross-iteration prefetch, contiguous 64B/thread y stores. y PLAIN layout.
// VGPR ~28-32; bigger per-thread tiles spill (R6/R8).
extern "C" __global__ __launch_bounds__(256) void k_transform(
    const float* __restrict__ in_feat, const float* __restrict__ W,
    const float* __restrict__ rs_out, __half* __restrict__ y, int N) {
  int tid = threadIdx.x;
  int wave = tid >> 6, lane = tid & 63;
  int bt = blockIdx.y * 4 + wave;     // 0..7
  int b = bt >> 2, t = bt & 3;
  int fh = blockIdx.z * 32;           // f half: 0 or 32
  int n = blockIdx.x * 64 + lane;

  const float* xp = in_feat + (size_t)(b * 256 + t) * (size_t)N;  // h=0 row
  size_t hstride = (size_t)4 * (size_t)N;

  float acc[32];
  #pragma unroll
  for (int f = 0; f < 32; ++f) acc[f] = 0.0f;

  bool ok = (n < N);

  float xcur[4], xnxt[4];
  #pragma unroll
  for (int u = 0; u < 4; ++u)
    xcur[u] = ok ? xp[(size_t)u * hstride + n] : 0.0f;

  #pragma unroll 1
  for (int h0 = 0; h0 < 60; h0 += 4) {
    #pragma unroll
    for (int u = 0; u < 4; ++u)
      xnxt[u] = ok ? xp[(size_t)(h0 + 4 + u) * hstride + n] : 0.0f;
    #pragma unroll
    for (int u = 0; u < 4; ++u) {
      const float* wrow = W + (h0 + u) * 64 + fh;   // uniform -> s_load
      #pragma unroll
      for (int f = 0; f < 32; ++f) acc[f] = fmaf(xcur[u], wrow[f], acc[f]);
    }
    #pragma unroll
    for (int u = 0; u < 4; ++u) xcur[u] = xnxt[u];
  }
  #pragma unroll
  for (int u = 0; u < 4; ++u) {
    const float* wrow = W + (60 + u) * 64 + fh;
    #pragma unroll
    for (int f = 0; f < 32; ++f) acc[f] = fmaf(xcur[u], wrow[f], acc[f]);
  }

  if (ok) {
    float rs = rs_out[n];
    union { unsigned int u[16]; uint4 v[4]; } pk;
    #pragma unroll
    for (int q = 0; q < 16; ++q) {
      __half2 h2 = __float22half2_rn(make_float2(acc[2 * q] * rs, acc[2 * q + 1] * rs));
      pk.u[q] = *(unsigned int*)&h2;
    }
    uint4* yp = (uint4*)(y + (size_t)n * 512 + bt * 64 + fh);
    #pragma unroll
    for (int q = 0; q < 4; ++q) yp[q] = pk.v[q];
  }
}

// Aggregate: 512 threads = 8 waves; wave handles 2 nodes (16-node tile, 33KB
// LDS -> 4 blocks/CU -> 32 waves/CU). Per edge: ONE uint4 from plain y (lane
// l = channels 8l..8l+7). LDS: accA (ch 8l..8l+3) -> col 4l, accB (ch
// 8l+4..8l+7) -> col 256+4l (the R9 8-way conflict level). Epilogue remaps
// channel c -> col = (c&4) ? 256+4*(c>>3)+(c&3) : 4*(c>>3)+(c&3).
extern "C" __global__ __launch_bounds__(512) void k_aggregate(
    const __half* __restrict__ y, const int* __restrict__ offs,
    const int* __restrict__ csr_src, const float* __restrict__ rs_in,
    const float* __restrict__ bvec, float* __restrict__ out, int N) {
  __shared__ float agg[16 * 513];
  int tid = threadIdx.x;
  int lane = tid & 63, wave = tid >> 6;   // 8 waves
  int n0 = blockIdx.x * 16;

#define LDE(i, s) uint4 u##i = ((const uint4*)(y + (size_t)(s) * 512))[lane];
#define ADE(i)                                                               \
  {                                                                          \
    float2 f;                                                                \
    f = __half22float2(*(const __half2*)&u##i.x); accA.x += f.x; accA.y += f.y; \
    f = __half22float2(*(const __half2*)&u##i.y); accA.z += f.x; accA.w += f.y; \
    f = __half22float2(*(const __half2*)&u##i.z); accB.x += f.x; accB.y += f.y; \
    f = __half22float2(*(const __half2*)&u##i.w); accB.z += f.x; accB.w += f.y; \
  }

  #pragma unroll
  for (int k = 0; k < 2; ++k) {
    int nl = k * 8 + wave;
    int n = n0 + nl;
    float4 accA = {0.f, 0.f, 0.f, 0.f};
    float4 accB = {0.f, 0.f, 0.f, 0.f};
    if (n < N) {
      int j0 = offs[n], j1 = offs[n + 1];
      for (int base = j0; base < j1; base += 64) {
        int idxv = csr_src[base + lane];  // coalesced block of up to 64 indices
        int m = j1 - base; if (m > 64) m = 64;
        int e = 0;
        for (; e + 7 < m; e += 8) {
          int s0 = __builtin_amdgcn_readlane(idxv, e);
          int s1 = __builtin_amdgcn_readlane(idxv, e + 1);
          int s2 = __builtin_amdgcn_readlane(idxv, e + 2);
          int s3 = __builtin_amdgcn_readlane(idxv, e + 3);
          int s4 = __builtin_amdgcn_readlane(idxv, e + 4);
          int s5 = __builtin_amdgcn_readlane(idxv, e + 5);
          int s6 = __builtin_amdgcn_readlane(idxv, e + 6);
          int s7 = __builtin_amdgcn_readlane(idxv, e + 7);
          LDE(0, s0); LDE(1, s1); LDE(2, s2); LDE(3, s3);
          LDE(4, s4); LDE(5, s5); LDE(6, s6); LDE(7, s7);
          ADE(0); ADE(1); ADE(2); ADE(3); ADE(4); ADE(5); ADE(6); ADE(7);
        }
        for (; e + 3 < m; e += 4) {
          int s0 = __builtin_amdgcn_readlane(idxv, e);
          int s1 = __builtin_amdgcn_readlane(idxv, e + 1);
          int s2 = __builtin_amdgcn_readlane(idxv, e + 2);
          int s3 = __builtin_amdgcn_readlane(idxv, e + 3);
          LDE(0, s0); LDE(1, s1); LDE(2, s2); LDE(3, s3);
          ADE(0); ADE(1); ADE(2); ADE(3);
        }
        for (; e < m; ++e) {
          int s0 = __builtin_amdgcn_readlane(idxv, e);
          LDE(0, s0); ADE(0);
        }
      }
    }
    *(float4*)&agg[nl * 513 + lane * 4] = accA;
    *(float4*)&agg[nl * 513 + 256 + lane * 4] = accB;
  }
#undef LDE
#undef ADE
  __syncthreads();

  // epilogue: scale, bias, relu, remap col, transpose-back to channel-major
  int nl = tid & 15;
  int r0 = tid >> 4;  // 0..31
  int n = n0 + nl;
  float rs = (n < N) ? rs_in[n] : 0.0f;
  #pragma unroll 4
  for (int it = 0; it < 16; ++it) {
    int c = it * 32 + r0;          // c = (b*4+t)*64 + f
    int l = c >> 3, j = c & 7;
    int col = (j < 4) ? (l << 2) + j : 256 + (l << 2) + (j - 4);
    float v = agg[nl * 513 + col];
    int f = c & 63, bt = c >> 6;
    int b = bt >> 2, t = bt & 3;
    v = v * rs + bvec[f];
    v = fmaxf(v, 0.0f);
    if (n < N) out[(size_t)((b * 64 + f) * 4 + t) * (size_t)N + n] = v;
  }
}

extern "C" void kernel_launch(void* const* d_in, const int* in_sizes, int n_in,
                              void* d_out, int out_size, void* d_ws, size_t ws_size,
                              hipStream_t stream) {
  const float* in_feat = (const float*)d_in[0];
  const int*   src     = (const int*)d_in[1];
  const int*   dst     = (const int*)d_in[2];
  const float* W       = (const float*)d_in[3];
  const float* bvec    = (const float*)d_in[4];
  float* out = (float*)d_out;

  int N = in_sizes[0] / 512;   // B*H*T = 2*64*4 = 512
  int E = in_sizes[1];

  int A  = (N + 64) & ~63;     // room for N+1 offsets, 64-aligned
  int EA = (E + 63) & ~63;
  int M  = (N + 255) / 256;    // scan blocks (<= 256 for N <= 65536)

  // layout: the three arrays needing zero-init come first (one memset)
  int*   deg_out_i = (int*)d_ws;        // [A]  zeroed
  int*   deg_in_i  = deg_out_i + A;     // [A]  zeroed
  int*   cursor    = deg_in_i + A;      // [A]  zeroed
  int*   offs      = cursor + A;        // [A] (N+1 used, fully written by scans)
  int*   bsum      = offs + A;          // [256]
  int*   boffs     = bsum + 256;        // [256]
  float* rs_out    = (float*)(boffs + 256);
  float* rs_in     = rs_out + A;
  int*   csr_src   = (int*)(rs_in + A); // [EA] (+slack: y follows, overreads safe)
  __half* y        = (__half*)(csr_src + EA); // [N*512] fp16, plain layout

  hipMemsetAsync(deg_out_i, 0, (size_t)(3 * A) * sizeof(int), stream);
  hipLaunchKernelGGL(k_deg, dim3((E + 255) / 256), dim3(256), 0, stream,
                     src, dst, deg_out_i, deg_in_i, E);
  hipLaunchKernelGGL(k_scan1, dim3(M), dim3(256), 0, stream,
                     deg_in_i, deg_out_i, bsum, rs_out, rs_in, N);
  hipLaunchKernelGGL(k_scan2, dim3(1), dim3(256), 0, stream, bsum, boffs, offs, M, N);
  hipLaunchKernelGGL(k_scan3, dim3(M), dim3(256), 0, stream, deg_in_i, boffs, offs, N);
  hipLaunchKernelGGL(k_scatter, dim3((E + 255) / 256), dim3(256), 0, stream,
                     src, dst, offs, cursor, csr_src, E);
  hipLaunchKernelGGL(k_transform, dim3((N + 63) / 64, 2, 2), dim3(256), 0, stream,
                     in_feat, W, rs_out, y, N);
  hipLaunchKernelGGL(k_aggregate, dim3((N + 15) / 16), dim3(512), 0, stream,
                     y, offs, csr_src, rs_in, bvec, out, N);
}